// Round 5
// baseline (496.216 us; speedup 1.0000x reference)
//
#include <hip/hip_runtime.h>
#include <hip/hip_bf16.h>

// ---------------- problem constants ----------------
#define B_    256
#define T_    250
#define NIN   700
#define NHID  512
#define NOUT  20
#define KT_N  11                 // k-tiles of 64 per segment: 704 = 11*64
#define MC_N  2000               // 64000 / 32 row-chunks
#define M_TOT (B_ * T_)          // 64000

typedef float  f32x2  __attribute__((ext_vector_type(2)));
typedef float  f32x4  __attribute__((ext_vector_type(4)));
typedef float  f32x16 __attribute__((ext_vector_type(16)));
typedef int    i32x2  __attribute__((ext_vector_type(2)));
typedef int    i32x4  __attribute__((ext_vector_type(4)));
typedef int    i32x8  __attribute__((ext_vector_type(8)));

// ---------------- workspace layout ----------------
// [0, 65,536,000)   : i_in  (M_TOT x NHID bf16)
// [+, 180,224,000)  : Apack fp8 fragment-major, ALL 4 segs precomputed
//                     word index = (kt*MC_N + mc)*2048 + seg*512 + half*256 + lane*4 + i
// [+, 1,441,792)    : Bpack fp8 fragment-major (4 segs)
// [+, 1,048,576)    : w_recT (512x512 f32)
// total ~248.3 MB
#define IIN_BYTES   ((size_t)M_TOT * NHID * 2)
#define APACK_OFF   IIN_BYTES
#define APACK_BYTES ((size_t)KT_N * MC_N * 4 * 2048)
#define BPACK_OFF   (APACK_OFF + APACK_BYTES)
#define BPACK_BYTES ((size_t)4 * KT_N * 16 * 64 * 32)
#define BPACK_WORDS (BPACK_BYTES / 4)                  // 360,448
#define WRECT_OFF   (BPACK_OFF + BPACK_BYTES)
#define BSEG        (KT_N * 16 * 512)                  // 90,112 words per B seg

// async global->LDS: 16B per lane, LDS dest = uniform base + lane*16
__device__ __forceinline__ void gload_lds16(const int* g, int* l) {
    __builtin_amdgcn_global_load_lds(
        (const __attribute__((address_space(1))) void*)g,
        (__attribute__((address_space(3))) void*)l,
        16, 0, 0);
}

// ---------------- kernel 1: pack B to fp8 fragment-major + transpose w_rec ----------------
__global__ __launch_bounds__(256) void kan_pack(
    const float* __restrict__ w_kan, const float* __restrict__ d1,
    const float* __restrict__ d2,    const float* __restrict__ d3,
    const float* __restrict__ w_rec,
    int* __restrict__ BpackW, float* __restrict__ wrecT)
{
    int idx = blockIdx.x * 256 + threadIdx.x;
    if (idx < (int)BPACK_WORDS) {
        int w   = idx;
        int c   = w >> 3;                  // 32-byte chunk index
        int jj  = (w & 7) * 4;             // byte offset within chunk
        int ln  = c & 31;
        int kh  = (c >> 5) & 1;
        int nt  = (c >> 6) & 15;
        int ks  = c >> 10;                 // seg*11 + kt
        int kt  = ks % 11;
        int seg = ks / 11;
        int n   = nt * 32 + ln;
        int kb  = kt * 64 + kh * 32 + jj;
        const float* wp = (seg == 0) ? w_kan : (seg == 1) ? d1 : (seg == 2) ? d2 : d3;
        float f0 = (kb + 0 < NIN) ? wp[(size_t)n * NIN + kb + 0] : 0.0f;
        float f1 = (kb + 1 < NIN) ? wp[(size_t)n * NIN + kb + 1] : 0.0f;
        float f2 = (kb + 2 < NIN) ? wp[(size_t)n * NIN + kb + 2] : 0.0f;
        float f3 = (kb + 3 < NIN) ? wp[(size_t)n * NIN + kb + 3] : 0.0f;
        int u = __builtin_amdgcn_cvt_pk_fp8_f32(f0, f1, 0, false);
        u     = __builtin_amdgcn_cvt_pk_fp8_f32(f2, f3, u, true);
        BpackW[w] = u;
    }
    if (idx < NHID * NHID) {
        int h  = idx & 511;
        int hp = idx >> 9;
        wrecT[(size_t)hp * NHID + h] = w_rec[(size_t)h * NHID + hp];
    }
}

// ---------------- kernel 2: pack x AND t1/t2/t3 to fp8 A-fragment-major ----------------
// Within-seg-block word offset for thread (kh,r,q), pair (q&1):
//   w0 = (q>>1)*256 + kh*128 + r*4 + (q&1)*2     ([half][lane][16B] order)
__global__ __launch_bounds__(256) void kan_packa(
    const float* __restrict__ x, int* __restrict__ Apack)
{
    int blk = blockIdx.x;          // mc*11 + kt
    int kt  = blk % KT_N;
    int mc  = blk / KT_N;
    int t   = threadIdx.x;
    int q   = t & 3;
    int r   = (t >> 2) & 31;
    int kh  = t >> 7;
    int k0  = kt * 64 + kh * 32 + q * 8;      // max 696
    const float* xr = x + (size_t)(mc * 32 + r) * NIN + k0;
    f32x4 v0 = *(const f32x4*)xr;             // always in-range (k0+3 <= 699)
    f32x4 v1 = {0.f, 0.f, 0.f, 0.f};
    if (k0 + 7 < NIN) v1 = *(const f32x4*)(xr + 4);

    float e[8] = {v0[0], v0[1], v0[2], v0[3], v1[0], v1[1], v1[2], v1[3]};
    float p1[8], p2[8], p3[8];
    #pragma unroll
    for (int u = 0; u < 8; ++u) {
        p1[u] = fminf(fabsf(e[u]), 1.0f);     // t1 = clip(|x|,0,1)
        p2[u] = p1[u] * p1[u];
        p3[u] = p2[u] * p1[u];
    }

    int* segbase = Apack + ((size_t)(kt * MC_N + mc)) * 2048;
    int  w0 = (q >> 1) * 256 + kh * 128 + r * 4 + (q & 1) * 2;
    // seg 0: raw x
    {
        int u0 = __builtin_amdgcn_cvt_pk_fp8_f32(e[0], e[1], 0, false);
        u0     = __builtin_amdgcn_cvt_pk_fp8_f32(e[2], e[3], u0, true);
        int u1 = __builtin_amdgcn_cvt_pk_fp8_f32(e[4], e[5], 0, false);
        u1     = __builtin_amdgcn_cvt_pk_fp8_f32(e[6], e[7], u1, true);
        *(i32x2*)(segbase + w0) = i32x2{u0, u1};
    }
    // seg 1: t1
    {
        int u0 = __builtin_amdgcn_cvt_pk_fp8_f32(p1[0], p1[1], 0, false);
        u0     = __builtin_amdgcn_cvt_pk_fp8_f32(p1[2], p1[3], u0, true);
        int u1 = __builtin_amdgcn_cvt_pk_fp8_f32(p1[4], p1[5], 0, false);
        u1     = __builtin_amdgcn_cvt_pk_fp8_f32(p1[6], p1[7], u1, true);
        *(i32x2*)(segbase + 512 + w0) = i32x2{u0, u1};
    }
    // seg 2: t1^2
    {
        int u0 = __builtin_amdgcn_cvt_pk_fp8_f32(p2[0], p2[1], 0, false);
        u0     = __builtin_amdgcn_cvt_pk_fp8_f32(p2[2], p2[3], u0, true);
        int u1 = __builtin_amdgcn_cvt_pk_fp8_f32(p2[4], p2[5], 0, false);
        u1     = __builtin_amdgcn_cvt_pk_fp8_f32(p2[6], p2[7], u1, true);
        *(i32x2*)(segbase + 1024 + w0) = i32x2{u0, u1};
    }
    // seg 3: t1^3
    {
        int u0 = __builtin_amdgcn_cvt_pk_fp8_f32(p3[0], p3[1], 0, false);
        u0     = __builtin_amdgcn_cvt_pk_fp8_f32(p3[2], p3[3], u0, true);
        int u1 = __builtin_amdgcn_cvt_pk_fp8_f32(p3[4], p3[5], 0, false);
        u1     = __builtin_amdgcn_cvt_pk_fp8_f32(p3[6], p3[7], u1, true);
        *(i32x2*)(segbase + 1536 + w0) = i32x2{u0, u1};
    }
}

// ---------------- kernel 3: fp8 GEMM, N-full blocks, 16 waves, TLP-first ----------------
// R2-R4 post-mortem: every schedule variant at 2 waves/SIMD in lockstep landed at
// MfmaUtil ~26% -- latency can't be scheduled away at HIP level with no TLP.
// New structure: one block = 128 rows x FULL N=512 (A read once, bx merged, no
// swizzle needed; B 1.4MB stays L2-hot). 1024 threads = 16 waves = 4 waves/SIMD.
// Wave (wm,wn) owns 32x128: acc[4] (64 VGPR). __launch_bounds__(1024,4) caps
// VGPR at 128 which forces per-phase JIT B loads; their L2 latency is hidden by
// 4-wave TLP, not by hand scheduling. One barrier + one (free) vmcnt(0) per kt;
// stage(kt+1) has a full iteration of MFMA to land.
__global__ __launch_bounds__(1024, 4) void kan_gemm(
    const int* __restrict__ Apack, const int* __restrict__ Bpack,
    __bf16* __restrict__ iin)
{
    __shared__ int lds[2][8192];              // 2 x 32 KB A tile (4 mc x 4 seg)

    const int tid  = threadIdx.x;
    const int lane = tid & 63;
    const int wave = tid >> 6;       // 0..15
    const int wm   = wave >> 2;      // 0..3 : 32-row chunk
    const int wn   = wave & 3;       // 0..3 : 128-col group
    const int by   = blockIdx.x;     // 0..499
    const int l31  = lane & 31;
    const int kh   = lane >> 5;
    const int lw   = lane * 4;       // lane word offset (16B stride)

    f32x16 acc[4];
    #pragma unroll
    for (int j = 0; j < 4; ++j)
        #pragma unroll
        for (int r = 0; r < 16; ++r)
            acc[j][r] = 0.0f;

    // ---- prologue: stage kt=0 into buf 0 (wave stages its 2KB slice) ----
    {
        const int* src = Apack + ((size_t)(by * 4)) * 2048 + wave * 512 + lw;
        int* dst = &lds[0][wave * 512];
        gload_lds16(src,       dst);
        gload_lds16(src + 256, dst + 256);
    }

    int buf = 0;
    #pragma unroll 1
    for (int kt = 0; kt < KT_N; ++kt) {
        // stage(kt) was issued one full iteration ago -> this wait is ~free
        asm volatile("s_waitcnt vmcnt(0)" ::: "memory");
        __builtin_amdgcn_s_barrier();          // all waves' stage(kt) landed

        // ---- stage next A tile into buf^1 (lands during this kt's MFMAs) ----
        if (kt + 1 < KT_N) {
            const int* src = Apack + ((size_t)((kt + 1) * MC_N + by * 4)) * 2048
                             + wave * 512 + lw;
            int* dst = &lds[buf ^ 1][wave * 512];
            gload_lds16(src,       dst);
            gload_lds16(src + 256, dst + 256);
        }

        const int* bb    = Bpack + ((size_t)(kt * 16 + wn * 4)) * 512 + lane * 8;
        const int  abase = wm * 2048;

        // ---- 4 seg-phases: JIT B loads + 1 A ds_read + 4 MFMA each ----
        #pragma unroll
        for (int s = 0; s < 4; ++s) {
            i32x8 Bj0 = *(const i32x8*)(bb + s * BSEG);
            i32x8 Bj1 = *(const i32x8*)(bb + s * BSEG + 512);
            i32x8 Bj2 = *(const i32x8*)(bb + s * BSEG + 1024);
            i32x8 Bj3 = *(const i32x8*)(bb + s * BSEG + 1536);
            i32x4 lo = *(const i32x4*)&lds[buf][abase + s * 512 + lw];
            i32x4 hi = *(const i32x4*)&lds[buf][abase + s * 512 + 256 + lw];
            i32x8 A = i32x8{lo[0], lo[1], lo[2], lo[3], hi[0], hi[1], hi[2], hi[3]};

            acc[0] = __builtin_amdgcn_mfma_scale_f32_32x32x64_f8f6f4(
                A, Bj0, acc[0], 0, 0, 0, 0x7f7f7f7f, 0, 0x7f7f7f7f);
            acc[1] = __builtin_amdgcn_mfma_scale_f32_32x32x64_f8f6f4(
                A, Bj1, acc[1], 0, 0, 0, 0x7f7f7f7f, 0, 0x7f7f7f7f);
            acc[2] = __builtin_amdgcn_mfma_scale_f32_32x32x64_f8f6f4(
                A, Bj2, acc[2], 0, 0, 0, 0x7f7f7f7f, 0, 0x7f7f7f7f);
            acc[3] = __builtin_amdgcn_mfma_scale_f32_32x32x64_f8f6f4(
                A, Bj3, acc[3], 0, 0, 0, 0x7f7f7f7f, 0, 0x7f7f7f7f);
        }
        buf ^= 1;
    }

    // ---- epilogue: 32x32 C/D layout col=lane&31, row=(r&3)+8*(r>>2)+4*(lane>>5) ----
    const int row0 = by * 128 + wm * 32 + kh * 4;
    const int col0 = wn * 128 + l31;
    #pragma unroll
    for (int j = 0; j < 4; ++j) {
        int c = col0 + j * 32;
        #pragma unroll
        for (int r = 0; r < 16; ++r) {
            int row = row0 + (r & 3) + 8 * (r >> 2);
            iin[(size_t)row * NHID + c] = (__bf16)acc[j][r];
        }
    }
}

// ---------------- kernel 4: adaptive-LIF scan, one wave per sample, PF=25 bf16 ----------------
#define PF 25
__global__ __launch_bounds__(64) void kan_scan(
    const __bf16* __restrict__ iin, const float* __restrict__ wrecT,
    const float* __restrict__ w_out, float* __restrict__ out)
{
    const int b    = blockIdx.x;
    const int lane = threadIdx.x;
    const __bf16* basep = iin + (size_t)b * T_ * NHID + lane * 8;
    #define LOADQ(t) (*(const i32x4*)(basep + (size_t)(t) * NHID))

    i32x4 q[PF];
    #pragma unroll
    for (int d = 0; d < PF; ++d) q[d] = LOADQ(d);

    float v1[8], a1[8];
    #pragma unroll
    for (int u = 0; u < 8; ++u) { v1[u] = 0.f; a1[u] = 0.f; }
    unsigned sm = 0;
    int anyprev = 0;
    float v_out = 0.f, acco = 0.f;

    #pragma unroll 1
    for (int t0 = 0; t0 < T_; t0 += PF) {
        #pragma unroll
        for (int j = 0; j < PF; ++j) {
            const int t = t0 + j;
            float cur[8];
            #pragma unroll
            for (int w = 0; w < 4; ++w) {
                int wv = q[j][w];
                cur[2 * w]     = __builtin_bit_cast(float, wv << 16);
                cur[2 * w + 1] = __builtin_bit_cast(float, wv & 0xffff0000);
            }
            if (t + PF < T_) q[j] = LOADQ(t + PF);

            if (anyprev) {           // rare path: recurrent input from prev spikes
                #pragma unroll
                for (int u = 0; u < 8; ++u) {
                    unsigned long long mu = __ballot((sm >> u) & 1u);
                    while (mu) {
                        int jl = __ffsll(mu) - 1; mu &= mu - 1;
                        const float* wr = wrecT + (size_t)(jl * 8 + u) * NHID + lane * 8;
                        f32x4 wa = *(const f32x4*)wr;
                        f32x4 wb = *(const f32x4*)(wr + 4);
                        cur[0] += wa[0]; cur[1] += wa[1]; cur[2] += wa[2]; cur[3] += wa[3];
                        cur[4] += wb[0]; cur[5] += wb[1]; cur[6] += wb[2]; cur[7] += wb[3];
                    }
                }
            }

            unsigned nm = 0;
            #pragma unroll
            for (int u = 0; u < 8; ++u) {
                float sp = ((sm >> u) & 1u) ? 1.0f : 0.0f;
                v1[u] = 0.95f * v1[u] + 0.05f * cur[u] - sp;
                a1[u] = 0.85f * a1[u] + 0.15f * sp;
                if (v1[u] - (1.0f + 0.05f * a1[u]) > 0.0f) nm |= (1u << u);
            }

            unsigned long long anyb = __ballot(nm != 0u);
            float io = 0.0f;
            if (anyb) {              // rare path: readout current from spikes
                #pragma unroll
                for (int u = 0; u < 8; ++u) {
                    unsigned long long mu = __ballot((nm >> u) & 1u);
                    while (mu) {
                        int jl = __ffsll(mu) - 1; mu &= mu - 1;
                        int unit = jl * 8 + u;
                        if (lane < NOUT) io += w_out[(size_t)lane * NHID + unit];
                    }
                }
            }

            v_out = 0.9f * v_out + io;
            float so = (v_out - 1.0f > 0.0f) ? 1.0f : 0.0f;
            v_out -= so;
            acco += v_out;

            sm = nm;
            anyprev = (anyb != 0ull);
        }
    }

    if (lane < NOUT) out[b * NOUT + lane] = acco * (1.0f / 250.0f);
}

// ---------------- launcher ----------------
extern "C" void kernel_launch(void* const* d_in, const int* in_sizes, int n_in,
                              void* d_out, int out_size, void* d_ws, size_t ws_size,
                              hipStream_t stream)
{
    const float* x     = (const float*)d_in[0];
    const float* w_kan = (const float*)d_in[1];
    const float* d1    = (const float*)d_in[2];
    const float* d2    = (const float*)d_in[3];
    const float* d3    = (const float*)d_in[4];
    const float* w_rec = (const float*)d_in[5];
    const float* w_out = (const float*)d_in[6];
    float* out = (float*)d_out;

    char*   ws    = (char*)d_ws;
    __bf16* iin   = (__bf16*)ws;
    int*    Apack = (int*)(ws + APACK_OFF);
    int*    Bpack = (int*)(ws + BPACK_OFF);
    float*  wrecT = (float*)(ws + WRECT_OFF);

    kan_pack<<<dim3((BPACK_WORDS + 255) / 256), 256, 0, stream>>>(
        w_kan, d1, d2, d3, w_rec, Bpack, wrecT);
    kan_packa<<<dim3(MC_N * KT_N), 256, 0, stream>>>(x, Apack);
    kan_gemm<<<dim3(M_TOT / 128), 1024, 0, stream>>>(Apack, Bpack, iin);
    kan_scan<<<dim3(B_), 64, 0, stream>>>(iin, wrecT, w_out, out);
}

// Round 6
// 392.637 us; speedup vs baseline: 1.2638x; 1.2638x over previous
//
#include <hip/hip_runtime.h>
#include <hip/hip_bf16.h>

// ---------------- problem constants ----------------
#define B_    256
#define T_    250
#define NIN   700
#define NHID  512
#define NOUT  20
#define KT_N  11                 // k-tiles of 64 per segment: 704 = 11*64
#define M_TOT (B_ * T_)          // 64000

typedef float  f32x2  __attribute__((ext_vector_type(2)));
typedef float  f32x4  __attribute__((ext_vector_type(4)));
typedef float  f32x16 __attribute__((ext_vector_type(16)));
typedef int    i32x2  __attribute__((ext_vector_type(2)));
typedef int    i32x4  __attribute__((ext_vector_type(4)));
typedef int    i32x8  __attribute__((ext_vector_type(8)));

// ---------------- workspace layout ----------------
// [0, 65,536,000)   : i_in  (M_TOT x NHID bf16)
// [+, 1,441,792)    : Bpack fp8 fragment-major (4 segs)
// [+, 1,048,576)    : w_recT (512x512 f32)
// total ~68 MB  (Apack intermediate eliminated -- x is converted in-kernel)
#define IIN_BYTES   ((size_t)M_TOT * NHID * 2)
#define BPACK_OFF   IIN_BYTES
#define BPACK_BYTES ((size_t)4 * KT_N * 16 * 64 * 32)
#define BPACK_WORDS (BPACK_BYTES / 4)                  // 360,448
#define WRECT_OFF   (BPACK_OFF + BPACK_BYTES)
#define BSEG        (KT_N * 16 * 512)                  // 90,112 words per B seg

// ---------------- kernel 1: pack B to fp8 fragment-major + transpose w_rec ----------------
__global__ __launch_bounds__(256) void kan_pack(
    const float* __restrict__ w_kan, const float* __restrict__ d1,
    const float* __restrict__ d2,    const float* __restrict__ d3,
    const float* __restrict__ w_rec,
    int* __restrict__ BpackW, float* __restrict__ wrecT)
{
    int idx = blockIdx.x * 256 + threadIdx.x;
    if (idx < (int)BPACK_WORDS) {
        int w   = idx;
        int c   = w >> 3;                  // 32-byte chunk index
        int jj  = (w & 7) * 4;             // byte offset within chunk
        int ln  = c & 31;
        int kh  = (c >> 5) & 1;
        int nt  = (c >> 6) & 15;
        int ks  = c >> 10;                 // seg*11 + kt
        int kt  = ks % 11;
        int seg = ks / 11;
        int n   = nt * 32 + ln;
        int kb  = kt * 64 + kh * 32 + jj;
        const float* wp = (seg == 0) ? w_kan : (seg == 1) ? d1 : (seg == 2) ? d2 : d3;
        float f0 = (kb + 0 < NIN) ? wp[(size_t)n * NIN + kb + 0] : 0.0f;
        float f1 = (kb + 1 < NIN) ? wp[(size_t)n * NIN + kb + 1] : 0.0f;
        float f2 = (kb + 2 < NIN) ? wp[(size_t)n * NIN + kb + 2] : 0.0f;
        float f3 = (kb + 3 < NIN) ? wp[(size_t)n * NIN + kb + 3] : 0.0f;
        int u = __builtin_amdgcn_cvt_pk_fp8_f32(f0, f1, 0, false);
        u     = __builtin_amdgcn_cvt_pk_fp8_f32(f2, f3, u, true);
        BpackW[w] = u;
    }
    if (idx < NHID * NHID) {
        int h  = idx & 511;
        int hp = idx >> 9;
        wrecT[(size_t)hp * NHID + h] = w_rec[(size_t)h * NHID + hp];
    }
}

// ---- pack 16 f32 -> 16 fp8 bytes (4 words) ----
__device__ __forceinline__ i32x4 pack16(const float* s) {
    i32x4 w;
    #pragma unroll
    for (int j = 0; j < 4; ++j) {
        int u = __builtin_amdgcn_cvt_pk_fp8_f32(s[4 * j + 0], s[4 * j + 1], 0, false);
        u     = __builtin_amdgcn_cvt_pk_fp8_f32(s[4 * j + 2], s[4 * j + 3], u, true);
        w[j] = u;
    }
    return w;
}

// ---- convert 16 x-values -> 4 seg fragments, store to LDS (sequential to cap regs) ----
__device__ __forceinline__ void conv_store(const float* e, int* dst) {
    *(i32x4*)(dst + 0) = pack16(e);                    // seg0: raw x
    float p1[16];
    #pragma unroll
    for (int i = 0; i < 16; ++i) p1[i] = fminf(fabsf(e[i]), 1.0f);
    *(i32x4*)(dst + 512) = pack16(p1);                 // seg1: t1
    float p2[16];
    #pragma unroll
    for (int i = 0; i < 16; ++i) p2[i] = p1[i] * p1[i];
    *(i32x4*)(dst + 1024) = pack16(p2);                // seg2: t1^2
    float p3[16];
    #pragma unroll
    for (int i = 0; i < 16; ++i) p3[i] = p2[i] * p1[i];
    *(i32x4*)(dst + 1536) = pack16(p3);                // seg3: t1^3
}

// ---------------- kernel 2: FUSED x->fp8 conversion + fp8 GEMM ----------------
// R5 post-mortem: precomputed-A structures all latency-bound at 19-26% MfmaUtil;
// only R0 (conversion VALU co-resident with MFMA) reached ~100% combined issue.
// This kernel: full-N block (128 rows x 512 cols), 8 waves of 64x... wave =
// 128 rows x 64 cols (acc[4][2] = 128 VGPR), __launch_bounds__(512,2) -> 256 VGPR
// budget (R3 proved B-regs stay live at this budget). Per kt: issue x(kt+1) loads
// (pinned above MFMAs by sched_barrier) -> 32 MFMAs from LDS[buf] + JIT L2-hot B
// -> convert x(kt+1) + ds_write LDS[buf^1] (hides x latency under MFMA) -> one
// __syncthreads. No Apack intermediate, no packa kernel, ws shrinks 248->68 MB.
__global__ __launch_bounds__(512, 2) void kan_gemm(
    const float* __restrict__ x, const int* __restrict__ Bpack,
    __bf16* __restrict__ iin)
{
    __shared__ int lds[2][8192];              // 2 x 32 KB: 4 mc-chunks x 4 segs x 512 words

    const int tid  = threadIdx.x;
    const int lane = tid & 63;
    const int wn   = tid >> 6;       // wave 0..7 : 64-col group
    const int by   = blockIdx.x;     // 0..499 : 128-row tile
    const int l31  = lane & 31;
    const int kh   = lane >> 5;

    // conversion mapping: t = mcL*128 + q2*32 + r31  (r fastest -> conflict-free LDS writes)
    const int r31v = tid & 31;
    const int q2   = (tid >> 5) & 3;
    const int mcL  = tid >> 7;
    const int xrow = by * 128 + mcL * 32 + r31v;
    const float* xr = x + (size_t)xrow * NIN;
    const int kf    = q2 * 16;                 // within-tile k offset of this thread's 16 elems
    const int wbase = mcL * 4 * 512 + (q2 & 1) * 256 + (q2 >> 1) * 128 + r31v * 4;

    f32x16 acc[4][2];
    #pragma unroll
    for (int c = 0; c < 4; ++c)
        #pragma unroll
        for (int j = 0; j < 2; ++j)
            #pragma unroll
            for (int r = 0; r < 16; ++r)
                acc[c][j][r] = 0.0f;

    // ---- prologue: load+convert kt=0 into buf 0 ----
    {
        float e[16];
        #pragma unroll
        for (int c = 0; c < 4; ++c) {
            int k = kf + c * 4;                // kt=0: always < 700
            f32x4 v = *(const f32x4*)(xr + k);
            e[c * 4 + 0] = v[0]; e[c * 4 + 1] = v[1];
            e[c * 4 + 2] = v[2]; e[c * 4 + 3] = v[3];
        }
        conv_store(e, &lds[0][wbase]);
    }
    __syncthreads();

    int buf = 0;
    #pragma unroll 1
    for (int kt = 0; kt < KT_N - 1; ++kt) {
        // ---- issue x loads for kt+1 (oldest vmem; consumed after MFMAs) ----
        f32x4 xv[4];
        #pragma unroll
        for (int c = 0; c < 4; ++c) {
            int k = (kt + 1) * 64 + kf + c * 4;
            xv[c] = (k < NIN) ? *(const f32x4*)(xr + k) : f32x4{0.f, 0.f, 0.f, 0.f};
        }
        __builtin_amdgcn_sched_barrier(0);     // keep loads above the MFMA section

        // ---- 32 MFMAs over LDS[buf] (4 segs x 4 chunks x 2 col-frags) ----
        #pragma unroll
        for (int s = 0; s < 4; ++s) {
            const int* bb = Bpack + (size_t)(kt * 16 + wn * 2) * 512
                            + (size_t)s * BSEG + lane * 8;
            i32x8 b0 = *(const i32x8*)bb;
            i32x8 b1 = *(const i32x8*)(bb + 512);
            #pragma unroll
            for (int c = 0; c < 4; ++c) {
                const int* ab = &lds[buf][(c * 4 + s) * 512 + lane * 4];
                i32x4 lo = *(const i32x4*)ab;
                i32x4 hi = *(const i32x4*)(ab + 256);
                i32x8 A = i32x8{lo[0], lo[1], lo[2], lo[3], hi[0], hi[1], hi[2], hi[3]};
                acc[c][0] = __builtin_amdgcn_mfma_scale_f32_32x32x64_f8f6f4(
                    A, b0, acc[c][0], 0, 0, 0, 0x7f7f7f7f, 0, 0x7f7f7f7f);
                acc[c][1] = __builtin_amdgcn_mfma_scale_f32_32x32x64_f8f6f4(
                    A, b1, acc[c][1], 0, 0, 0, 0x7f7f7f7f, 0, 0x7f7f7f7f);
            }
        }

        // ---- convert kt+1 -> LDS[buf^1] (x-load latency was hidden under MFMAs) ----
        {
            float e[16];
            #pragma unroll
            for (int c = 0; c < 4; ++c) {
                e[c * 4 + 0] = xv[c][0]; e[c * 4 + 1] = xv[c][1];
                e[c * 4 + 2] = xv[c][2]; e[c * 4 + 3] = xv[c][3];
            }
            conv_store(e, &lds[buf ^ 1][wbase]);
        }
        __syncthreads();                       // writes visible; all reads of buf done
        buf ^= 1;
    }

    // ---- final k-tile (kt = 10), no staging ----
    {
        const int kt = KT_N - 1;
        #pragma unroll
        for (int s = 0; s < 4; ++s) {
            const int* bb = Bpack + (size_t)(kt * 16 + wn * 2) * 512
                            + (size_t)s * BSEG + lane * 8;
            i32x8 b0 = *(const i32x8*)bb;
            i32x8 b1 = *(const i32x8*)(bb + 512);
            #pragma unroll
            for (int c = 0; c < 4; ++c) {
                const int* ab = &lds[buf][(c * 4 + s) * 512 + lane * 4];
                i32x4 lo = *(const i32x4*)ab;
                i32x4 hi = *(const i32x4*)(ab + 256);
                i32x8 A = i32x8{lo[0], lo[1], lo[2], lo[3], hi[0], hi[1], hi[2], hi[3]};
                acc[c][0] = __builtin_amdgcn_mfma_scale_f32_32x32x64_f8f6f4(
                    A, b0, acc[c][0], 0, 0, 0, 0x7f7f7f7f, 0, 0x7f7f7f7f);
                acc[c][1] = __builtin_amdgcn_mfma_scale_f32_32x32x64_f8f6f4(
                    A, b1, acc[c][1], 0, 0, 0, 0x7f7f7f7f, 0, 0x7f7f7f7f);
            }
        }
    }

    // ---- epilogue: 32x32 C/D layout col=lane&31, row=(r&3)+8*(r>>2)+4*(lane>>5) ----
    #pragma unroll
    for (int c = 0; c < 4; ++c) {
        int m0 = by * 128 + c * 32 + kh * 4;
        #pragma unroll
        for (int j = 0; j < 2; ++j) {
            int col = wn * 64 + j * 32 + l31;
            #pragma unroll
            for (int r = 0; r < 16; ++r) {
                int row = m0 + (r & 3) + 8 * (r >> 2);
                iin[(size_t)row * NHID + col] = (__bf16)acc[c][j][r];
            }
        }
    }
}

// ---------------- kernel 3: adaptive-LIF scan, one wave per sample, PF=25 bf16 ----------------
#define PF 25
__global__ __launch_bounds__(64) void kan_scan(
    const __bf16* __restrict__ iin, const float* __restrict__ wrecT,
    const float* __restrict__ w_out, float* __restrict__ out)
{
    const int b    = blockIdx.x;
    const int lane = threadIdx.x;
    const __bf16* basep = iin + (size_t)b * T_ * NHID + lane * 8;
    #define LOADQ(t) (*(const i32x4*)(basep + (size_t)(t) * NHID))

    i32x4 q[PF];
    #pragma unroll
    for (int d = 0; d < PF; ++d) q[d] = LOADQ(d);

    float v1[8], a1[8];
    #pragma unroll
    for (int u = 0; u < 8; ++u) { v1[u] = 0.f; a1[u] = 0.f; }
    unsigned sm = 0;
    int anyprev = 0;
    float v_out = 0.f, acco = 0.f;

    #pragma unroll 1
    for (int t0 = 0; t0 < T_; t0 += PF) {
        #pragma unroll
        for (int j = 0; j < PF; ++j) {
            const int t = t0 + j;
            float cur[8];
            #pragma unroll
            for (int w = 0; w < 4; ++w) {
                int wv = q[j][w];
                cur[2 * w]     = __builtin_bit_cast(float, wv << 16);
                cur[2 * w + 1] = __builtin_bit_cast(float, wv & 0xffff0000);
            }
            if (t + PF < T_) q[j] = LOADQ(t + PF);

            if (anyprev) {           // rare path: recurrent input from prev spikes
                #pragma unroll
                for (int u = 0; u < 8; ++u) {
                    unsigned long long mu = __ballot((sm >> u) & 1u);
                    while (mu) {
                        int jl = __ffsll(mu) - 1; mu &= mu - 1;
                        const float* wr = wrecT + (size_t)(jl * 8 + u) * NHID + lane * 8;
                        f32x4 wa = *(const f32x4*)wr;
                        f32x4 wb = *(const f32x4*)(wr + 4);
                        cur[0] += wa[0]; cur[1] += wa[1]; cur[2] += wa[2]; cur[3] += wa[3];
                        cur[4] += wb[0]; cur[5] += wb[1]; cur[6] += wb[2]; cur[7] += wb[3];
                    }
                }
            }

            unsigned nm = 0;
            #pragma unroll
            for (int u = 0; u < 8; ++u) {
                float sp = ((sm >> u) & 1u) ? 1.0f : 0.0f;
                v1[u] = 0.95f * v1[u] + 0.05f * cur[u] - sp;
                a1[u] = 0.85f * a1[u] + 0.15f * sp;
                if (v1[u] - (1.0f + 0.05f * a1[u]) > 0.0f) nm |= (1u << u);
            }

            unsigned long long anyb = __ballot(nm != 0u);
            float io = 0.0f;
            if (anyb) {              // rare path: readout current from spikes
                #pragma unroll
                for (int u = 0; u < 8; ++u) {
                    unsigned long long mu = __ballot((nm >> u) & 1u);
                    while (mu) {
                        int jl = __ffsll(mu) - 1; mu &= mu - 1;
                        int unit = jl * 8 + u;
                        if (lane < NOUT) io += w_out[(size_t)lane * NHID + unit];
                    }
                }
            }

            v_out = 0.9f * v_out + io;
            float so = (v_out - 1.0f > 0.0f) ? 1.0f : 0.0f;
            v_out -= so;
            acco += v_out;

            sm = nm;
            anyprev = (anyb != 0ull);
        }
    }

    if (lane < NOUT) out[b * NOUT + lane] = acco * (1.0f / 250.0f);
}

// ---------------- launcher ----------------
extern "C" void kernel_launch(void* const* d_in, const int* in_sizes, int n_in,
                              void* d_out, int out_size, void* d_ws, size_t ws_size,
                              hipStream_t stream)
{
    const float* x     = (const float*)d_in[0];
    const float* w_kan = (const float*)d_in[1];
    const float* d1    = (const float*)d_in[2];
    const float* d2    = (const float*)d_in[3];
    const float* d3    = (const float*)d_in[4];
    const float* w_rec = (const float*)d_in[5];
    const float* w_out = (const float*)d_in[6];
    float* out = (float*)d_out;

    char*   ws    = (char*)d_ws;
    __bf16* iin   = (__bf16*)ws;
    int*    Bpack = (int*)(ws + BPACK_OFF);
    float*  wrecT = (float*)(ws + WRECT_OFF);

    kan_pack<<<dim3((BPACK_WORDS + 255) / 256), 256, 0, stream>>>(
        w_kan, d1, d2, d3, w_rec, Bpack, wrecT);
    kan_gemm<<<dim3(M_TOT / 128), 512, 0, stream>>>(x, Bpack, iin);
    kan_scan<<<dim3(B_), 64, 0, stream>>>(iin, wrecT, w_out, out);
}